// Round 7
// baseline (8088.641 us; speedup 1.0000x reference)
//
#include <hip/hip_runtime.h>
#include <hip/hip_bf16.h>
#include <stdint.h>

// Shape2DPainterNet forward: LSTM(64 steps, D=64) + heads + JAX-exact categorical sampling.
// B=16384, T=64, D=64, V+1=32001 (all derived from in_sizes at launch).
//
// R7 change vs R6 (which spilled): __launch_bounds__(1024, 4) on k_lstm64.
// R6's plain __launch_bounds__(1024) let the compiler target 8 waves/EU (2 blocks/CU)
// -> 64-VGPR cap -> the 4-deep weight ring spilled to scratch (WRITE_SIZE 15.9 GB,
// VALUBusy 9%). Grid is 1 block/CU by construction, so 4 waves/EU is the right
// occupancy: VGPR cap 512, ring stays in registers. All else identical to R6.

typedef float v2f __attribute__((ext_vector_type(2)));

// ---------------- threefry2x32 (bit-exact JAX impl) ----------------
__device__ __forceinline__ uint32_t rotl32(uint32_t x, uint32_t r) {
  return (x << r) | (x >> (32u - r));
}

__device__ __forceinline__ uint2 threefry2x32(uint32_t k0, uint32_t k1,
                                              uint32_t x0, uint32_t x1) {
  const uint32_t k2 = k0 ^ k1 ^ 0x1BD11BDAu;
  x0 += k0; x1 += k1;
#define TFR(r) { x0 += x1; x1 = rotl32(x1, r); x1 ^= x0; }
  TFR(13u) TFR(15u) TFR(26u) TFR(6u)
  x0 += k1; x1 += k2 + 1u;
  TFR(17u) TFR(29u) TFR(16u) TFR(24u)
  x0 += k2; x1 += k0 + 2u;
  TFR(13u) TFR(15u) TFR(26u) TFR(6u)
  x0 += k0; x1 += k1 + 3u;
  TFR(17u) TFR(29u) TFR(16u) TFR(24u)
  x0 += k1; x1 += k2 + 4u;
  TFR(13u) TFR(15u) TFR(26u) TFR(6u)
  x0 += k2; x1 += k0 + 5u;
#undef TFR
  return make_uint2(x0, x1);
}

__device__ __forceinline__ float gumbel_jax(uint32_t k0, uint32_t k1, uint32_t idx) {
  uint2 o = threefry2x32(k0, k1, 0u, idx);
  uint32_t bits = o.x ^ o.y;
  float f = __uint_as_float(0x3f800000u | (bits >> 9)) - 1.0f;   // [0,1)
  const float tiny = 1.1754943508222875e-38f;                    // finfo(f32).tiny
  float u = fmaxf(tiny, f + tiny);
  return -logf(-logf(u));
}

template <int C>
__device__ __forceinline__ void sample_head(const float* lg, uint32_t k0, uint32_t k1,
                                            int row, int& samp, float& lp) {
  float best = -3.402823466e38f;
  int bi = 0;
  float lsel = lg[0];
  float m = lg[0];
  #pragma unroll
  for (int c = 0; c < C; ++c) {
    float t = lg[c] + gumbel_jax(k0, k1, (uint32_t)(row * C + c));
    if (t > best) { best = t; bi = c; lsel = lg[c]; }
    m = fmaxf(m, lg[c]);
  }
  float s = 0.f;
  #pragma unroll
  for (int c = 0; c < C; ++c) s += expf(lg[c] - m);
  samp = bi;
  lp = lsel - m - logf(s);
}

__device__ __forceinline__ float sigmoidf_(float x) { return 1.0f / (1.0f + expf(-x)); }

// ---------------- Kernel 1: embedW[v][d][gi] = (embed @ W_ih + b_ih + b_hh) ----------------
__global__ __launch_bounds__(1024) void k_embedw(
    const float* __restrict__ embed, const float* __restrict__ W_ih,
    const float* __restrict__ b_ih, const float* __restrict__ b_hh,
    float* __restrict__ embedWG, int NV) {
  __shared__ float sW[64 * 256];            // W_ih[k][g], 64 KB
  const int tid = threadIdx.x;
  for (int i = tid; i < 4096; i += 1024)
    ((float4*)sW)[i] = ((const float4*)W_ih)[i];
  __syncthreads();
  const int d   = tid & 63;
  const int gi  = (tid >> 6) & 3;
  const int vr0 = tid >> 8;
  const int g   = gi * 64 + d;
  const float bias = b_ih[g] + b_hh[g];
  const int vbase = blockIdx.x * 126;
  for (int it = 0; it < 32; ++it) {
    int lr = it * 4 + vr0;
    int v  = vbase + lr;
    if (lr < 126 && v < NV) {
      const float* e = embed + (size_t)v * 64;
      float acc = bias;
      #pragma unroll 8
      for (int k = 0; k < 64; ++k) acc = fmaf(e[k], sW[k * 256 + g], acc);
      embedWG[(size_t)v * 256 + d * 4 + gi] = acc;
    }
  }
}

// ---------------- Kernel 1b: wt[k*256 + u*4 + gi] = W_hh[k*256 + gi*64 + u] ------------
__global__ __launch_bounds__(1024) void k_wt(const float* __restrict__ W_hh,
                                             float* __restrict__ wt) {
  const int idx = blockIdx.x * 1024 + threadIdx.x;
  if (idx < 16384) {
    const int k = idx >> 8, g = idx & 255;
    const int gi = g >> 6, u = g & 63;
    wt[k * 256 + u * 4 + gi] = W_hh[idx];
  }
}

// ---------------- Kernel 2: LSTM, 64 steps; W via VMEM broadcast ring ----------------
// 1 block = 64 batch rows. lane l = row; wave wid owns units d0..d0+3 (16 gate-weights/k).
// LDS: sH double-buffered h^T [unit][row]; one barrier per t-step.
// launch_bounds(1024, 4): exactly 1 block/CU -> VGPR cap 512, ring stays in registers.
__global__ __launch_bounds__(1024, 4) void k_lstm64(
    const int* __restrict__ inst, const float* __restrict__ wt,
    const float* __restrict__ embedWG, float* __restrict__ eOut) {
  __shared__ float sH[2][4096];

  const int tid = threadIdx.x;
  const int l   = tid & 63;
  const int wid = tid >> 6;
  const int d0  = wid << 2;
  const int rbase = blockIdx.x << 6;
  const size_t r  = (size_t)rbase + l;

  // wave-uniform weight base (same address in every lane -> 1 coalesced request)
  const float* __restrict__ wgp = wt + wid * 16;

  for (int i = tid; i < 4096; i += 1024) sH[0][i] = 0.f;

  // preload W ring: slot j holds k === j (mod 4)
  float4 ws[4][4];
  #pragma unroll
  for (int j = 0; j < 4; ++j) {
    const float4* wp4 = (const float4*)(wgp + j * 256);
    ws[j][0] = wp4[0]; ws[j][1] = wp4[1]; ws[j][2] = wp4[2]; ws[j][3] = wp4[3];
  }

  float c4[4] = {0.f, 0.f, 0.f, 0.f};
  float4 gc[4], gn[4];
  int tok1;
  {
    int tok0 = inst[r * 64 + 0];
    tok1     = inst[r * 64 + 1];
    const float4* p = (const float4*)(embedWG + (size_t)tok0 * 256 + d0 * 4);
    gc[0] = p[0]; gc[1] = p[1]; gc[2] = p[2]; gc[3] = p[3];
  }
  __syncthreads();

  int cur = 0;
  for (int t = 0; t < 64; ++t) {
    const float* sHc = sH[cur];
    float*       sHn = sH[cur ^ 1];

    // acc init = x-part (bit-exact order: x-part first, then ascending-k h-products)
    float a[4][4];
    #pragma unroll
    for (int u = 0; u < 4; ++u) {
      a[u][0] = gc[u].x; a[u][1] = gc[u].y; a[u][2] = gc[u].z; a[u][3] = gc[u].w;
    }

    // prefetch gates(t+1) and token(t+2); gc is dead now -> regs recycle into gn
    {
      const float4* p = (const float4*)(embedWG + (size_t)tok1 * 256 + d0 * 4);
      gn[0] = p[0]; gn[1] = p[1]; gn[2] = p[2]; gn[3] = p[3];
    }
    int tok2 = inst[r * 64 + ((t + 2) & 63)];

    for (int kb = 0; kb < 64; kb += 4) {
      #pragma unroll
      for (int j = 0; j < 4; ++j) {
        float hk = sHc[(kb + j) * 64 + l];              // conflict-free b32
        float4 wu0 = ws[j][0], wu1 = ws[j][1], wu2 = ws[j][2], wu3 = ws[j][3];
        // reload slot j for k' = kb+j+4 (wraps mod 64 -> ring ready for next t too)
        const float4* wp4 = (const float4*)(wgp + ((kb + j + 4) & 63) * 256);
        ws[j][0] = wp4[0]; ws[j][1] = wp4[1]; ws[j][2] = wp4[2]; ws[j][3] = wp4[3];
        a[0][0] = fmaf(hk, wu0.x, a[0][0]);
        a[0][1] = fmaf(hk, wu0.y, a[0][1]);
        a[0][2] = fmaf(hk, wu0.z, a[0][2]);
        a[0][3] = fmaf(hk, wu0.w, a[0][3]);
        a[1][0] = fmaf(hk, wu1.x, a[1][0]);
        a[1][1] = fmaf(hk, wu1.y, a[1][1]);
        a[1][2] = fmaf(hk, wu1.z, a[1][2]);
        a[1][3] = fmaf(hk, wu1.w, a[1][3]);
        a[2][0] = fmaf(hk, wu2.x, a[2][0]);
        a[2][1] = fmaf(hk, wu2.y, a[2][1]);
        a[2][2] = fmaf(hk, wu2.z, a[2][2]);
        a[2][3] = fmaf(hk, wu2.w, a[2][3]);
        a[3][0] = fmaf(hk, wu3.x, a[3][0]);
        a[3][1] = fmaf(hk, wu3.y, a[3][1]);
        a[3][2] = fmaf(hk, wu3.z, a[3][2]);
        a[3][3] = fmaf(hk, wu3.w, a[3][3]);
      }
    }

    // nonlinearity: torch gate order i,f,g,o
    #pragma unroll
    for (int u = 0; u < 4; ++u) {
      float ig = sigmoidf_(a[u][0]);
      float fg = sigmoidf_(a[u][1]);
      float gg = tanhf(a[u][2]);
      float og = sigmoidf_(a[u][3]);
      float cn = fg * c4[u] + ig * gg;
      c4[u] = cn;
      sHn[(d0 + u) * 64 + l] = og * tanhf(cn);
    }
    __syncthreads();                     // h(t+1) visible; old buffer free to overwrite
    cur ^= 1;
    gc[0] = gn[0]; gc[1] = gn[1]; gc[2] = gn[2]; gc[3] = gn[3];
    tok1 = tok2;
  }

  // write final hidden state (in sH[0] after 64 flips), coalesced
  for (int i = tid; i < 4096; i += 1024) {
    int rr = i >> 6, dd = i & 63;
    eOut[(size_t)(rbase + rr) * 64 + dd] = sH[0][dd * 64 + rr];
  }
}

// ---------------- Kernel 3: attention MLP logits, one thread per (row, cell) ----------------
__global__ __launch_bounds__(256) void k_attlog(
    const float* __restrict__ eOut, const float* __restrict__ canvas,
    const float* __restrict__ Wr1, const float* __restrict__ br1,
    const float* __restrict__ Wr2, const float* __restrict__ br2,
    float* __restrict__ attL, int total) {
  const int gid = blockIdx.x * 256 + threadIdx.x;
  if (gid >= total) return;
  const int rrow = gid / 25, cell = gid - rrow * 25;
  const float* e  = eOut + (size_t)rrow * 64;
  const float* cv = canvas + (size_t)rrow * 100 + cell * 4;
  float cv0 = cv[0], cv1 = cv[1], cv2 = cv[2], cv3 = cv[3];

  float h[32];
  #pragma unroll
  for (int j4 = 0; j4 < 8; ++j4) {
    float4 b4 = ((const float4*)br1)[j4];
    float4 w64 = ((const float4*)(Wr1 + 64 * 32))[j4];
    float4 w65 = ((const float4*)(Wr1 + 65 * 32))[j4];
    float4 w66 = ((const float4*)(Wr1 + 66 * 32))[j4];
    float4 w67 = ((const float4*)(Wr1 + 67 * 32))[j4];
    h[j4*4+0] = fmaf(cv3, w67.x, fmaf(cv2, w66.x, fmaf(cv1, w65.x, fmaf(cv0, w64.x, b4.x))));
    h[j4*4+1] = fmaf(cv3, w67.y, fmaf(cv2, w66.y, fmaf(cv1, w65.y, fmaf(cv0, w64.y, b4.y))));
    h[j4*4+2] = fmaf(cv3, w67.z, fmaf(cv2, w66.z, fmaf(cv1, w65.z, fmaf(cv0, w64.z, b4.z))));
    h[j4*4+3] = fmaf(cv3, w67.w, fmaf(cv2, w66.w, fmaf(cv1, w65.w, fmaf(cv0, w64.w, b4.w))));
  }
  for (int k = 0; k < 64; ++k) {
    float ek = e[k];
    const float4* wrow = (const float4*)(Wr1 + k * 32);
    #pragma unroll
    for (int j4 = 0; j4 < 8; ++j4) {
      float4 w = wrow[j4];
      h[j4*4+0] = fmaf(ek, w.x, h[j4*4+0]);
      h[j4*4+1] = fmaf(ek, w.y, h[j4*4+1]);
      h[j4*4+2] = fmaf(ek, w.z, h[j4*4+2]);
      h[j4*4+3] = fmaf(ek, w.w, h[j4*4+3]);
    }
  }
  float logit = br2[0];
  #pragma unroll
  for (int j = 0; j < 32; ++j) logit = fmaf(fmaxf(h[j], 0.f), Wr2[j], logit);
  attL[gid] = logit;
}

// ---------------- Kernel 4: heads + sampling + index_join, one thread per row ----------------
__global__ __launch_bounds__(256) void k_heads(
    const float* __restrict__ eOut, const float* __restrict__ canvas,
    const int* __restrict__ inst_type,
    const float* __restrict__ Wc, const float* __restrict__ bc,
    const float* __restrict__ Wsh, const float* __restrict__ bsh,
    const float* __restrict__ Wa, const float* __restrict__ ba,
    const float* __restrict__ Wl, const float* __restrict__ bl,
    const float* __restrict__ Wr, const float* __restrict__ br,
    const float* __restrict__ attL, float* __restrict__ out, int B) {
  const int r = blockIdx.x * 256 + threadIdx.x;
  if (r >= B) return;
  const float* e = eOut + (size_t)r * 64;

  uint2 kc  = threefry2x32(0u, 42u, 0u, 0u);
  uint2 ksh = threefry2x32(0u, 42u, 0u, 1u);
  uint2 kac = threefry2x32(0u, 42u, 0u, 2u);
  uint2 kab = threefry2x32(0u, 42u, 0u, 3u);
  uint2 krl = threefry2x32(0u, 42u, 0u, 4u);
  uint2 kat = threefry2x32(0u, 42u, 0u, 5u);

  float lc[3]  = {bc[0], bc[1], bc[2]};
  float lsh[3] = {bsh[0], bsh[1], bsh[2]};
  float lac[2] = {ba[0], ba[1]};
  float ll[25];
  #pragma unroll
  for (int j = 0; j < 25; ++j) ll[j] = bl[j];
  float lrr[8];
  #pragma unroll
  for (int j = 0; j < 8; ++j) lrr[j] = br[j];

  for (int k = 0; k < 64; ++k) {
    float ek = e[k];
    #pragma unroll
    for (int j = 0; j < 3; ++j)  lc[j]  = fmaf(ek, Wc[k * 3 + j],  lc[j]);
    #pragma unroll
    for (int j = 0; j < 3; ++j)  lsh[j] = fmaf(ek, Wsh[k * 3 + j], lsh[j]);
    #pragma unroll
    for (int j = 0; j < 2; ++j)  lac[j] = fmaf(ek, Wa[k * 2 + j],  lac[j]);
    #pragma unroll
    for (int j = 0; j < 25; ++j) ll[j]  = fmaf(ek, Wl[k * 25 + j], ll[j]);
    #pragma unroll
    for (int j = 0; j < 8; ++j)  lrr[j] = fmaf(ek, Wr[k * 8 + j],  lrr[j]);
  }

  int s_color, s_shape, s_act, s_abs, s_rel, s_att;
  float lp_color, lp_shape, lp_act, lp_abs, lp_rel, lp_att;
  sample_head<3>(lc,  kc.x,  kc.y,  r, s_color, lp_color);
  sample_head<3>(lsh, ksh.x, ksh.y, r, s_shape, lp_shape);
  sample_head<2>(lac, kac.x, kac.y, r, s_act,   lp_act);
  sample_head<25>(ll, kab.x, kab.y, r, s_abs,   lp_abs);
  sample_head<8>(lrr, krl.x, krl.y, r, s_rel,   lp_rel);

  float lat[25];
  #pragma unroll
  for (int j = 0; j < 25; ++j) lat[j] = attL[(size_t)r * 25 + j];
  sample_head<25>(lat, kat.x, kat.y, r, s_att, lp_att);

  const float* cvp = canvas + (size_t)r * 100 + s_att * 4;
  int ref_r = (int)cvp[2];
  int ref_c = (int)cvp[3];
  int dr = (int)((0x22001120u >> (4 * s_rel)) & 15u) - 1;
  int dc = (int)((0x20200211u >> (4 * s_rel)) & 15u) - 1;
  int rel_loc = (ref_r + dr) * 5 + (ref_c + dc);

  bool isrel = (inst_type[r] == 2);
  out[(size_t)r * 5 + 0] = lp_color;
  out[(size_t)r * 5 + 1] = lp_shape;
  out[(size_t)r * 5 + 2] = lp_act;
  out[(size_t)r * 5 + 3] = isrel ? lp_rel : lp_abs;
  out[(size_t)r * 5 + 4] = isrel ? lp_att : 0.f;
  out[(size_t)B * 5 + r] = (float)(isrel ? rel_loc : s_abs);
}

// ---------------- launch ----------------
extern "C" void kernel_launch(void* const* d_in, const int* in_sizes, int n_in,
                              void* d_out, int out_size, void* d_ws, size_t ws_size,
                              hipStream_t stream) {
  (void)n_in; (void)out_size; (void)ws_size;
  const int*   inst      = (const int*)  d_in[0];
  const float* canvas    = (const float*)d_in[1];
  const int*   inst_type = (const int*)  d_in[2];
  const float* embed     = (const float*)d_in[3];
  const float* W_ih      = (const float*)d_in[4];
  const float* W_hh      = (const float*)d_in[5];
  const float* b_ih      = (const float*)d_in[6];
  const float* b_hh      = (const float*)d_in[7];
  const float* Wc  = (const float*)d_in[8];  const float* bc  = (const float*)d_in[9];
  const float* Wsh = (const float*)d_in[10]; const float* bsh = (const float*)d_in[11];
  const float* Wa  = (const float*)d_in[12]; const float* ba  = (const float*)d_in[13];
  const float* Wl  = (const float*)d_in[14]; const float* bl  = (const float*)d_in[15];
  const float* Wr  = (const float*)d_in[16]; const float* br  = (const float*)d_in[17];
  const float* Wr1 = (const float*)d_in[18]; const float* br1 = (const float*)d_in[19];
  const float* Wr2 = (const float*)d_in[20]; const float* br2 = (const float*)d_in[21];

  const int B  = in_sizes[0] / 64;   // 16384
  const int NV = in_sizes[3] / 64;   // 32001

  // workspace: embedW (NV*256 f32 ~31.3MB) | eOut (B*64 ~4MB) | attL (B*25 ~1.6MB) | wt (64KB)
  float* embedWG = (float*)d_ws;
  float* eOut    = embedWG + (size_t)NV * 256;
  float* attL    = eOut + (size_t)B * 64;
  float* wtbuf   = attL + (size_t)B * 25;
  float* out     = (float*)d_out;

  k_embedw<<<(NV + 125) / 126, 1024, 0, stream>>>(embed, W_ih, b_ih, b_hh, embedWG, NV);
  k_wt<<<16, 1024, 0, stream>>>(W_hh, wtbuf);
  k_lstm64<<<B / 64, 1024, 0, stream>>>(inst, wtbuf, embedWG, eOut);
  {
    int total = B * 25;
    k_attlog<<<(total + 255) / 256, 256, 0, stream>>>(eOut, canvas, Wr1, br1, Wr2, br2,
                                                      attL, total);
  }
  k_heads<<<(B + 255) / 256, 256, 0, stream>>>(eOut, canvas, inst_type,
                                               Wc, bc, Wsh, bsh, Wa, ba, Wl, bl, Wr, br,
                                               attL, out, B);
}

// Round 8
// 7539.125 us; speedup vs baseline: 1.0729x; 1.0729x over previous
//
#include <hip/hip_runtime.h>
#include <hip/hip_bf16.h>
#include <stdint.h>

// Shape2DPainterNet forward: LSTM(64 steps, D=64) + heads + JAX-exact categorical sampling.
// B=16384, T=64, D=64, V+1=32001 (all derived from in_sizes at launch).
//
// R8 change vs R7: pin occupancy with amdgpu_waves_per_eu(4,4).
// R7's __launch_bounds__(1024,4) only sets MIN waves/EU; the compiler still targeted
// 8 waves/EU (2 blocks/CU) -> 64-VGPR cap -> the weight ring spilled (WRITE_SIZE
// 15.7 GB scratch, VALUBusy 9%). Grid is 1 block/CU by construction, so max=4 too:
// one 1024-thread block/CU, VGPR budget 512, ring stays in registers.
// All else identical to R6/R7 (numerics bit-identical to passing R3/R4).

typedef float v2f __attribute__((ext_vector_type(2)));

// ---------------- threefry2x32 (bit-exact JAX impl) ----------------
__device__ __forceinline__ uint32_t rotl32(uint32_t x, uint32_t r) {
  return (x << r) | (x >> (32u - r));
}

__device__ __forceinline__ uint2 threefry2x32(uint32_t k0, uint32_t k1,
                                              uint32_t x0, uint32_t x1) {
  const uint32_t k2 = k0 ^ k1 ^ 0x1BD11BDAu;
  x0 += k0; x1 += k1;
#define TFR(r) { x0 += x1; x1 = rotl32(x1, r); x1 ^= x0; }
  TFR(13u) TFR(15u) TFR(26u) TFR(6u)
  x0 += k1; x1 += k2 + 1u;
  TFR(17u) TFR(29u) TFR(16u) TFR(24u)
  x0 += k2; x1 += k0 + 2u;
  TFR(13u) TFR(15u) TFR(26u) TFR(6u)
  x0 += k0; x1 += k1 + 3u;
  TFR(17u) TFR(29u) TFR(16u) TFR(24u)
  x0 += k1; x1 += k2 + 4u;
  TFR(13u) TFR(15u) TFR(26u) TFR(6u)
  x0 += k2; x1 += k0 + 5u;
#undef TFR
  return make_uint2(x0, x1);
}

__device__ __forceinline__ float gumbel_jax(uint32_t k0, uint32_t k1, uint32_t idx) {
  uint2 o = threefry2x32(k0, k1, 0u, idx);
  uint32_t bits = o.x ^ o.y;
  float f = __uint_as_float(0x3f800000u | (bits >> 9)) - 1.0f;   // [0,1)
  const float tiny = 1.1754943508222875e-38f;                    // finfo(f32).tiny
  float u = fmaxf(tiny, f + tiny);
  return -logf(-logf(u));
}

template <int C>
__device__ __forceinline__ void sample_head(const float* lg, uint32_t k0, uint32_t k1,
                                            int row, int& samp, float& lp) {
  float best = -3.402823466e38f;
  int bi = 0;
  float lsel = lg[0];
  float m = lg[0];
  #pragma unroll
  for (int c = 0; c < C; ++c) {
    float t = lg[c] + gumbel_jax(k0, k1, (uint32_t)(row * C + c));
    if (t > best) { best = t; bi = c; lsel = lg[c]; }
    m = fmaxf(m, lg[c]);
  }
  float s = 0.f;
  #pragma unroll
  for (int c = 0; c < C; ++c) s += expf(lg[c] - m);
  samp = bi;
  lp = lsel - m - logf(s);
}

__device__ __forceinline__ float sigmoidf_(float x) { return 1.0f / (1.0f + expf(-x)); }

// ---------------- Kernel 1: embedW[v][d][gi] = (embed @ W_ih + b_ih + b_hh) ----------------
__global__ __launch_bounds__(1024) void k_embedw(
    const float* __restrict__ embed, const float* __restrict__ W_ih,
    const float* __restrict__ b_ih, const float* __restrict__ b_hh,
    float* __restrict__ embedWG, int NV) {
  __shared__ float sW[64 * 256];            // W_ih[k][g], 64 KB
  const int tid = threadIdx.x;
  for (int i = tid; i < 4096; i += 1024)
    ((float4*)sW)[i] = ((const float4*)W_ih)[i];
  __syncthreads();
  const int d   = tid & 63;
  const int gi  = (tid >> 6) & 3;
  const int vr0 = tid >> 8;
  const int g   = gi * 64 + d;
  const float bias = b_ih[g] + b_hh[g];
  const int vbase = blockIdx.x * 126;
  for (int it = 0; it < 32; ++it) {
    int lr = it * 4 + vr0;
    int v  = vbase + lr;
    if (lr < 126 && v < NV) {
      const float* e = embed + (size_t)v * 64;
      float acc = bias;
      #pragma unroll 8
      for (int k = 0; k < 64; ++k) acc = fmaf(e[k], sW[k * 256 + g], acc);
      embedWG[(size_t)v * 256 + d * 4 + gi] = acc;
    }
  }
}

// ---------------- Kernel 1b: wt[k*256 + u*4 + gi] = W_hh[k*256 + gi*64 + u] ------------
__global__ __launch_bounds__(1024) void k_wt(const float* __restrict__ W_hh,
                                             float* __restrict__ wt) {
  const int idx = blockIdx.x * 1024 + threadIdx.x;
  if (idx < 16384) {
    const int k = idx >> 8, g = idx & 255;
    const int gi = g >> 6, u = g & 63;
    wt[k * 256 + u * 4 + gi] = W_hh[idx];
  }
}

// ---------------- Kernel 2: LSTM, 64 steps; W via VMEM broadcast ring ----------------
// 1 block = 64 batch rows. lane l = row; wave wid owns units d0..d0+3 (16 gate-weights/k).
// LDS: sH double-buffered h^T [unit][row]; one barrier per t-step.
// amdgpu_waves_per_eu(4,4): exactly 1 block/CU -> VGPR budget 512, ring in registers.
__global__ __launch_bounds__(1024)
__attribute__((amdgpu_waves_per_eu(4, 4)))
void k_lstm64(
    const int* __restrict__ inst, const float* __restrict__ wt,
    const float* __restrict__ embedWG, float* __restrict__ eOut) {
  __shared__ float sH[2][4096];

  const int tid = threadIdx.x;
  const int l   = tid & 63;
  const int wid = tid >> 6;
  const int d0  = wid << 2;
  const int rbase = blockIdx.x << 6;
  const size_t r  = (size_t)rbase + l;

  // wave-uniform weight base (same address in every lane -> 1 coalesced request)
  const float* __restrict__ wgp = wt + wid * 16;

  for (int i = tid; i < 4096; i += 1024) sH[0][i] = 0.f;

  // preload W ring: slot j holds k === j (mod 4)
  float4 ws[4][4];
  #pragma unroll
  for (int j = 0; j < 4; ++j) {
    const float4* wp4 = (const float4*)(wgp + j * 256);
    ws[j][0] = wp4[0]; ws[j][1] = wp4[1]; ws[j][2] = wp4[2]; ws[j][3] = wp4[3];
  }

  float c4[4] = {0.f, 0.f, 0.f, 0.f};
  float4 gc[4], gn[4];
  int tok1;
  {
    int tok0 = inst[r * 64 + 0];
    tok1     = inst[r * 64 + 1];
    const float4* p = (const float4*)(embedWG + (size_t)tok0 * 256 + d0 * 4);
    gc[0] = p[0]; gc[1] = p[1]; gc[2] = p[2]; gc[3] = p[3];
  }
  __syncthreads();

  int cur = 0;
  for (int t = 0; t < 64; ++t) {
    const float* sHc = sH[cur];
    float*       sHn = sH[cur ^ 1];

    // acc init = x-part (bit-exact order: x-part first, then ascending-k h-products)
    float a[4][4];
    #pragma unroll
    for (int u = 0; u < 4; ++u) {
      a[u][0] = gc[u].x; a[u][1] = gc[u].y; a[u][2] = gc[u].z; a[u][3] = gc[u].w;
    }

    // prefetch gates(t+1) and token(t+2); gc is dead now -> regs recycle into gn
    {
      const float4* p = (const float4*)(embedWG + (size_t)tok1 * 256 + d0 * 4);
      gn[0] = p[0]; gn[1] = p[1]; gn[2] = p[2]; gn[3] = p[3];
    }
    int tok2 = inst[r * 64 + ((t + 2) & 63)];

    for (int kb = 0; kb < 64; kb += 4) {
      #pragma unroll
      for (int j = 0; j < 4; ++j) {
        float hk = sHc[(kb + j) * 64 + l];              // conflict-free b32
        float4 wu0 = ws[j][0], wu1 = ws[j][1], wu2 = ws[j][2], wu3 = ws[j][3];
        // reload slot j for k' = kb+j+4 (wraps mod 64 -> ring ready for next t too)
        const float4* wp4 = (const float4*)(wgp + ((kb + j + 4) & 63) * 256);
        ws[j][0] = wp4[0]; ws[j][1] = wp4[1]; ws[j][2] = wp4[2]; ws[j][3] = wp4[3];
        a[0][0] = fmaf(hk, wu0.x, a[0][0]);
        a[0][1] = fmaf(hk, wu0.y, a[0][1]);
        a[0][2] = fmaf(hk, wu0.z, a[0][2]);
        a[0][3] = fmaf(hk, wu0.w, a[0][3]);
        a[1][0] = fmaf(hk, wu1.x, a[1][0]);
        a[1][1] = fmaf(hk, wu1.y, a[1][1]);
        a[1][2] = fmaf(hk, wu1.z, a[1][2]);
        a[1][3] = fmaf(hk, wu1.w, a[1][3]);
        a[2][0] = fmaf(hk, wu2.x, a[2][0]);
        a[2][1] = fmaf(hk, wu2.y, a[2][1]);
        a[2][2] = fmaf(hk, wu2.z, a[2][2]);
        a[2][3] = fmaf(hk, wu2.w, a[2][3]);
        a[3][0] = fmaf(hk, wu3.x, a[3][0]);
        a[3][1] = fmaf(hk, wu3.y, a[3][1]);
        a[3][2] = fmaf(hk, wu3.z, a[3][2]);
        a[3][3] = fmaf(hk, wu3.w, a[3][3]);
      }
    }

    // nonlinearity: torch gate order i,f,g,o
    #pragma unroll
    for (int u = 0; u < 4; ++u) {
      float ig = sigmoidf_(a[u][0]);
      float fg = sigmoidf_(a[u][1]);
      float gg = tanhf(a[u][2]);
      float og = sigmoidf_(a[u][3]);
      float cn = fg * c4[u] + ig * gg;
      c4[u] = cn;
      sHn[(d0 + u) * 64 + l] = og * tanhf(cn);
    }
    __syncthreads();                     // h(t+1) visible; old buffer free to overwrite
    cur ^= 1;
    gc[0] = gn[0]; gc[1] = gn[1]; gc[2] = gn[2]; gc[3] = gn[3];
    tok1 = tok2;
  }

  // write final hidden state (in sH[0] after 64 flips), coalesced
  for (int i = tid; i < 4096; i += 1024) {
    int rr = i >> 6, dd = i & 63;
    eOut[(size_t)(rbase + rr) * 64 + dd] = sH[0][dd * 64 + rr];
  }
}

// ---------------- Kernel 3: attention MLP logits, one thread per (row, cell) ----------------
__global__ __launch_bounds__(256) void k_attlog(
    const float* __restrict__ eOut, const float* __restrict__ canvas,
    const float* __restrict__ Wr1, const float* __restrict__ br1,
    const float* __restrict__ Wr2, const float* __restrict__ br2,
    float* __restrict__ attL, int total) {
  const int gid = blockIdx.x * 256 + threadIdx.x;
  if (gid >= total) return;
  const int rrow = gid / 25, cell = gid - rrow * 25;
  const float* e  = eOut + (size_t)rrow * 64;
  const float* cv = canvas + (size_t)rrow * 100 + cell * 4;
  float cv0 = cv[0], cv1 = cv[1], cv2 = cv[2], cv3 = cv[3];

  float h[32];
  #pragma unroll
  for (int j4 = 0; j4 < 8; ++j4) {
    float4 b4 = ((const float4*)br1)[j4];
    float4 w64 = ((const float4*)(Wr1 + 64 * 32))[j4];
    float4 w65 = ((const float4*)(Wr1 + 65 * 32))[j4];
    float4 w66 = ((const float4*)(Wr1 + 66 * 32))[j4];
    float4 w67 = ((const float4*)(Wr1 + 67 * 32))[j4];
    h[j4*4+0] = fmaf(cv3, w67.x, fmaf(cv2, w66.x, fmaf(cv1, w65.x, fmaf(cv0, w64.x, b4.x))));
    h[j4*4+1] = fmaf(cv3, w67.y, fmaf(cv2, w66.y, fmaf(cv1, w65.y, fmaf(cv0, w64.y, b4.y))));
    h[j4*4+2] = fmaf(cv3, w67.z, fmaf(cv2, w66.z, fmaf(cv1, w65.z, fmaf(cv0, w64.z, b4.z))));
    h[j4*4+3] = fmaf(cv3, w67.w, fmaf(cv2, w66.w, fmaf(cv1, w65.w, fmaf(cv0, w64.w, b4.w))));
  }
  for (int k = 0; k < 64; ++k) {
    float ek = e[k];
    const float4* wrow = (const float4*)(Wr1 + k * 32);
    #pragma unroll
    for (int j4 = 0; j4 < 8; ++j4) {
      float4 w = wrow[j4];
      h[j4*4+0] = fmaf(ek, w.x, h[j4*4+0]);
      h[j4*4+1] = fmaf(ek, w.y, h[j4*4+1]);
      h[j4*4+2] = fmaf(ek, w.z, h[j4*4+2]);
      h[j4*4+3] = fmaf(ek, w.w, h[j4*4+3]);
    }
  }
  float logit = br2[0];
  #pragma unroll
  for (int j = 0; j < 32; ++j) logit = fmaf(fmaxf(h[j], 0.f), Wr2[j], logit);
  attL[gid] = logit;
}

// ---------------- Kernel 4: heads + sampling + index_join, one thread per row ----------------
__global__ __launch_bounds__(256) void k_heads(
    const float* __restrict__ eOut, const float* __restrict__ canvas,
    const int* __restrict__ inst_type,
    const float* __restrict__ Wc, const float* __restrict__ bc,
    const float* __restrict__ Wsh, const float* __restrict__ bsh,
    const float* __restrict__ Wa, const float* __restrict__ ba,
    const float* __restrict__ Wl, const float* __restrict__ bl,
    const float* __restrict__ Wr, const float* __restrict__ br,
    const float* __restrict__ attL, float* __restrict__ out, int B) {
  const int r = blockIdx.x * 256 + threadIdx.x;
  if (r >= B) return;
  const float* e = eOut + (size_t)r * 64;

  uint2 kc  = threefry2x32(0u, 42u, 0u, 0u);
  uint2 ksh = threefry2x32(0u, 42u, 0u, 1u);
  uint2 kac = threefry2x32(0u, 42u, 0u, 2u);
  uint2 kab = threefry2x32(0u, 42u, 0u, 3u);
  uint2 krl = threefry2x32(0u, 42u, 0u, 4u);
  uint2 kat = threefry2x32(0u, 42u, 0u, 5u);

  float lc[3]  = {bc[0], bc[1], bc[2]};
  float lsh[3] = {bsh[0], bsh[1], bsh[2]};
  float lac[2] = {ba[0], ba[1]};
  float ll[25];
  #pragma unroll
  for (int j = 0; j < 25; ++j) ll[j] = bl[j];
  float lrr[8];
  #pragma unroll
  for (int j = 0; j < 8; ++j) lrr[j] = br[j];

  for (int k = 0; k < 64; ++k) {
    float ek = e[k];
    #pragma unroll
    for (int j = 0; j < 3; ++j)  lc[j]  = fmaf(ek, Wc[k * 3 + j],  lc[j]);
    #pragma unroll
    for (int j = 0; j < 3; ++j)  lsh[j] = fmaf(ek, Wsh[k * 3 + j], lsh[j]);
    #pragma unroll
    for (int j = 0; j < 2; ++j)  lac[j] = fmaf(ek, Wa[k * 2 + j],  lac[j]);
    #pragma unroll
    for (int j = 0; j < 25; ++j) ll[j]  = fmaf(ek, Wl[k * 25 + j], ll[j]);
    #pragma unroll
    for (int j = 0; j < 8; ++j)  lrr[j] = fmaf(ek, Wr[k * 8 + j],  lrr[j]);
  }

  int s_color, s_shape, s_act, s_abs, s_rel, s_att;
  float lp_color, lp_shape, lp_act, lp_abs, lp_rel, lp_att;
  sample_head<3>(lc,  kc.x,  kc.y,  r, s_color, lp_color);
  sample_head<3>(lsh, ksh.x, ksh.y, r, s_shape, lp_shape);
  sample_head<2>(lac, kac.x, kac.y, r, s_act,   lp_act);
  sample_head<25>(ll, kab.x, kab.y, r, s_abs,   lp_abs);
  sample_head<8>(lrr, krl.x, krl.y, r, s_rel,   lp_rel);

  float lat[25];
  #pragma unroll
  for (int j = 0; j < 25; ++j) lat[j] = attL[(size_t)r * 25 + j];
  sample_head<25>(lat, kat.x, kat.y, r, s_att, lp_att);

  const float* cvp = canvas + (size_t)r * 100 + s_att * 4;
  int ref_r = (int)cvp[2];
  int ref_c = (int)cvp[3];
  int dr = (int)((0x22001120u >> (4 * s_rel)) & 15u) - 1;
  int dc = (int)((0x20200211u >> (4 * s_rel)) & 15u) - 1;
  int rel_loc = (ref_r + dr) * 5 + (ref_c + dc);

  bool isrel = (inst_type[r] == 2);
  out[(size_t)r * 5 + 0] = lp_color;
  out[(size_t)r * 5 + 1] = lp_shape;
  out[(size_t)r * 5 + 2] = lp_act;
  out[(size_t)r * 5 + 3] = isrel ? lp_rel : lp_abs;
  out[(size_t)r * 5 + 4] = isrel ? lp_att : 0.f;
  out[(size_t)B * 5 + r] = (float)(isrel ? rel_loc : s_abs);
}

// ---------------- launch ----------------
extern "C" void kernel_launch(void* const* d_in, const int* in_sizes, int n_in,
                              void* d_out, int out_size, void* d_ws, size_t ws_size,
                              hipStream_t stream) {
  (void)n_in; (void)out_size; (void)ws_size;
  const int*   inst      = (const int*)  d_in[0];
  const float* canvas    = (const float*)d_in[1];
  const int*   inst_type = (const int*)  d_in[2];
  const float* embed     = (const float*)d_in[3];
  const float* W_ih      = (const float*)d_in[4];
  const float* W_hh      = (const float*)d_in[5];
  const float* b_ih      = (const float*)d_in[6];
  const float* b_hh      = (const float*)d_in[7];
  const float* Wc  = (const float*)d_in[8];  const float* bc  = (const float*)d_in[9];
  const float* Wsh = (const float*)d_in[10]; const float* bsh = (const float*)d_in[11];
  const float* Wa  = (const float*)d_in[12]; const float* ba  = (const float*)d_in[13];
  const float* Wl  = (const float*)d_in[14]; const float* bl  = (const float*)d_in[15];
  const float* Wr  = (const float*)d_in[16]; const float* br  = (const float*)d_in[17];
  const float* Wr1 = (const float*)d_in[18]; const float* br1 = (const float*)d_in[19];
  const float* Wr2 = (const float*)d_in[20]; const float* br2 = (const float*)d_in[21];

  const int B  = in_sizes[0] / 64;   // 16384
  const int NV = in_sizes[3] / 64;   // 32001

  // workspace: embedW (NV*256 f32 ~31.3MB) | eOut (B*64 ~4MB) | attL (B*25 ~1.6MB) | wt (64KB)
  float* embedWG = (float*)d_ws;
  float* eOut    = embedWG + (size_t)NV * 256;
  float* attL    = eOut + (size_t)B * 64;
  float* wtbuf   = attL + (size_t)B * 25;
  float* out     = (float*)d_out;

  k_embedw<<<(NV + 125) / 126, 1024, 0, stream>>>(embed, W_ih, b_ih, b_hh, embedWG, NV);
  k_wt<<<16, 1024, 0, stream>>>(W_hh, wtbuf);
  k_lstm64<<<B / 64, 1024, 0, stream>>>(inst, wtbuf, embedWG, eOut);
  {
    int total = B * 25;
    k_attlog<<<(total + 255) / 256, 256, 0, stream>>>(eOut, canvas, Wr1, br1, Wr2, br2,
                                                      attL, total);
  }
  k_heads<<<(B + 255) / 256, 256, 0, stream>>>(eOut, canvas, inst_type,
                                               Wc, bc, Wsh, bsh, Wa, ba, Wl, bl, Wr, br,
                                               attL, out, B);
}

// Round 9
// 2313.746 us; speedup vs baseline: 3.4959x; 3.2584x over previous
//
#include <hip/hip_runtime.h>
#include <hip/hip_bf16.h>
#include <stdint.h>

// Shape2DPainterNet forward: LSTM(64 steps, D=64) + heads + JAX-exact categorical sampling.
// B=16384, T=64, D=64, V+1=32001 (all derived from in_sizes at launch).
//
// R9 restructure: 1024-thread blocks forced a 64-VGPR compiler budget (R6-R8 spills;
// even R3's VGPR=32 implies scratch in the hot loop). New shape: 256-thread block
// (4 waves) owns 16 rows; grid = B/16 = 1024 = 4 blocks/CU. Lane = (row l&15,
// unit-quarter l>>4) -> acc 16 regs, W via per-lane global_load_dwordx4 (16-way
// shared addresses, vmcnt pipe, 1-deep prefetch), h in LDS [unit][row] stride 16
// (4-lane same-address broadcast reads = conflict-free). 4-wave barriers.
// Numerics bit-identical to passing R3/R4 (same op order, same gate math).

// ---------------- threefry2x32 (bit-exact JAX impl) ----------------
__device__ __forceinline__ uint32_t rotl32(uint32_t x, uint32_t r) {
  return (x << r) | (x >> (32u - r));
}

__device__ __forceinline__ uint2 threefry2x32(uint32_t k0, uint32_t k1,
                                              uint32_t x0, uint32_t x1) {
  const uint32_t k2 = k0 ^ k1 ^ 0x1BD11BDAu;
  x0 += k0; x1 += k1;
#define TFR(r) { x0 += x1; x1 = rotl32(x1, r); x1 ^= x0; }
  TFR(13u) TFR(15u) TFR(26u) TFR(6u)
  x0 += k1; x1 += k2 + 1u;
  TFR(17u) TFR(29u) TFR(16u) TFR(24u)
  x0 += k2; x1 += k0 + 2u;
  TFR(13u) TFR(15u) TFR(26u) TFR(6u)
  x0 += k0; x1 += k1 + 3u;
  TFR(17u) TFR(29u) TFR(16u) TFR(24u)
  x0 += k1; x1 += k2 + 4u;
  TFR(13u) TFR(15u) TFR(26u) TFR(6u)
  x0 += k2; x1 += k0 + 5u;
#undef TFR
  return make_uint2(x0, x1);
}

__device__ __forceinline__ float gumbel_jax(uint32_t k0, uint32_t k1, uint32_t idx) {
  uint2 o = threefry2x32(k0, k1, 0u, idx);
  uint32_t bits = o.x ^ o.y;
  float f = __uint_as_float(0x3f800000u | (bits >> 9)) - 1.0f;   // [0,1)
  const float tiny = 1.1754943508222875e-38f;                    // finfo(f32).tiny
  float u = fmaxf(tiny, f + tiny);
  return -logf(-logf(u));
}

template <int C>
__device__ __forceinline__ void sample_head(const float* lg, uint32_t k0, uint32_t k1,
                                            int row, int& samp, float& lp) {
  float best = -3.402823466e38f;
  int bi = 0;
  float lsel = lg[0];
  float m = lg[0];
  #pragma unroll
  for (int c = 0; c < C; ++c) {
    float t = lg[c] + gumbel_jax(k0, k1, (uint32_t)(row * C + c));
    if (t > best) { best = t; bi = c; lsel = lg[c]; }
    m = fmaxf(m, lg[c]);
  }
  float s = 0.f;
  #pragma unroll
  for (int c = 0; c < C; ++c) s += expf(lg[c] - m);
  samp = bi;
  lp = lsel - m - logf(s);
}

__device__ __forceinline__ float sigmoidf_(float x) { return 1.0f / (1.0f + expf(-x)); }

// ---------------- Kernel 1: embedW[v][d][gi] = (embed @ W_ih + b_ih + b_hh) ----------------
__global__ __launch_bounds__(1024) void k_embedw(
    const float* __restrict__ embed, const float* __restrict__ W_ih,
    const float* __restrict__ b_ih, const float* __restrict__ b_hh,
    float* __restrict__ embedWG, int NV) {
  __shared__ float sW[64 * 256];            // W_ih[k][g], 64 KB
  const int tid = threadIdx.x;
  for (int i = tid; i < 4096; i += 1024)
    ((float4*)sW)[i] = ((const float4*)W_ih)[i];
  __syncthreads();
  const int d   = tid & 63;
  const int gi  = (tid >> 6) & 3;
  const int vr0 = tid >> 8;
  const int g   = gi * 64 + d;
  const float bias = b_ih[g] + b_hh[g];
  const int vbase = blockIdx.x * 126;
  for (int it = 0; it < 32; ++it) {
    int lr = it * 4 + vr0;
    int v  = vbase + lr;
    if (lr < 126 && v < NV) {
      const float* e = embed + (size_t)v * 64;
      float acc = bias;
      #pragma unroll 8
      for (int k = 0; k < 64; ++k) acc = fmaf(e[k], sW[k * 256 + g], acc);
      embedWG[(size_t)v * 256 + d * 4 + gi] = acc;
    }
  }
}

// ---------------- Kernel 1b: wt[k*256 + u*4 + gi] = W_hh[k*256 + gi*64 + u] ------------
__global__ __launch_bounds__(1024) void k_wt(const float* __restrict__ W_hh,
                                             float* __restrict__ wt) {
  const int idx = blockIdx.x * 1024 + threadIdx.x;
  if (idx < 16384) {
    const int k = idx >> 8, g = idx & 255;
    const int gi = g >> 6, u = g & 63;
    wt[k * 256 + u * 4 + gi] = W_hh[idx];
  }
}

// ---------------- Kernel 2: LSTM, 64 steps; 256-thread block = 16 rows ----------------
// Lane l: row rr = l&15, unit-quarter uu = l>>4; wave w covers units 16w..16w+15.
// Each lane: 4 units x 4 gates for ONE row (acc 16 regs). W per-lane dwordx4 x4,
// 1-deep prefetch (vmcnt pipe). h in LDS [unit][row] stride 16, dbuf, 1 barrier/t.
__global__ __launch_bounds__(256) void k_lstm64(
    const int* __restrict__ inst, const float* __restrict__ wt,
    const float* __restrict__ embedWG, float* __restrict__ eOut) {
  __shared__ float hs[2][1024];

  const int tid = threadIdx.x;
  const int w   = tid >> 6;
  const int l   = tid & 63;
  const int rr  = l & 15;
  const int uu  = l >> 4;
  const int ub  = w * 16 + uu * 4;      // first of this lane's 4 units
  const int rbase = blockIdx.x << 4;
  const int rowg  = rbase + rr;

  for (int i = tid; i < 1024; i += 256) hs[0][i] = 0.f;

  const float4* __restrict__ wt4 = (const float4*)wt;       // [k*64 + u]
  const float4* __restrict__ eg4 = (const float4*)embedWG;  // [v*64 + u]

  float c0 = 0.f, c1 = 0.f, c2 = 0.f, c3 = 0.f;
  float4 gn0, gn1, gn2, gn3;
  int tok1;
  {
    int tok0 = inst[(size_t)rowg * 64 + 0];
    tok1     = inst[(size_t)rowg * 64 + 1];
    const float4* p = eg4 + (size_t)tok0 * 64 + ub;
    gn0 = p[0]; gn1 = p[1]; gn2 = p[2]; gn3 = p[3];     // gates(t=0)
  }

  // preload W(k=0)
  float4 wc0 = wt4[ub], wc1 = wt4[ub + 1], wc2 = wt4[ub + 2], wc3 = wt4[ub + 3];

  __syncthreads();

  int cur = 0;
  for (int t = 0; t < 64; ++t) {
    const float* hc = hs[cur];
    float*       hn = hs[cur ^ 1];

    // acc init = x-part (bit-exact order: x-part first, then ascending-k h-products)
    float4 A0 = gn0, A1 = gn1, A2 = gn2, A3 = gn3;

    // prefetch gates(t+1) and token(t+2)
    {
      const float4* p = eg4 + (size_t)tok1 * 64 + ub;
      gn0 = p[0]; gn1 = p[1]; gn2 = p[2]; gn3 = p[3];
    }
    int tok2 = inst[(size_t)rowg * 64 + ((t + 2) & 63)];

    for (int k = 0; k < 64; ++k) {
      float hk = hc[k * 16 + rr];                  // 4-lane broadcast, conflict-free
      // issue next-k W loads first so latency hides under the 16 FMAs
      const float4* wp = wt4 + ((k + 1) & 63) * 64 + ub;   // wraps -> primed for next t
      float4 n0 = wp[0], n1 = wp[1], n2 = wp[2], n3 = wp[3];
      A0.x = fmaf(hk, wc0.x, A0.x); A0.y = fmaf(hk, wc0.y, A0.y);
      A0.z = fmaf(hk, wc0.z, A0.z); A0.w = fmaf(hk, wc0.w, A0.w);
      A1.x = fmaf(hk, wc1.x, A1.x); A1.y = fmaf(hk, wc1.y, A1.y);
      A1.z = fmaf(hk, wc1.z, A1.z); A1.w = fmaf(hk, wc1.w, A1.w);
      A2.x = fmaf(hk, wc2.x, A2.x); A2.y = fmaf(hk, wc2.y, A2.y);
      A2.z = fmaf(hk, wc2.z, A2.z); A2.w = fmaf(hk, wc2.w, A2.w);
      A3.x = fmaf(hk, wc3.x, A3.x); A3.y = fmaf(hk, wc3.y, A3.y);
      A3.z = fmaf(hk, wc3.z, A3.z); A3.w = fmaf(hk, wc3.w, A3.w);
      wc0 = n0; wc1 = n1; wc2 = n2; wc3 = n3;
    }

    // nonlinearity: torch gate order i,f,g,o (components x,y,z,w)
    {
      float ig = sigmoidf_(A0.x), fg = sigmoidf_(A0.y);
      float gg = tanhf(A0.z),     og = sigmoidf_(A0.w);
      float cn = fg * c0 + ig * gg; c0 = cn;
      hn[(ub + 0) * 16 + rr] = og * tanhf(cn);
    }
    {
      float ig = sigmoidf_(A1.x), fg = sigmoidf_(A1.y);
      float gg = tanhf(A1.z),     og = sigmoidf_(A1.w);
      float cn = fg * c1 + ig * gg; c1 = cn;
      hn[(ub + 1) * 16 + rr] = og * tanhf(cn);
    }
    {
      float ig = sigmoidf_(A2.x), fg = sigmoidf_(A2.y);
      float gg = tanhf(A2.z),     og = sigmoidf_(A2.w);
      float cn = fg * c2 + ig * gg; c2 = cn;
      hn[(ub + 2) * 16 + rr] = og * tanhf(cn);
    }
    {
      float ig = sigmoidf_(A3.x), fg = sigmoidf_(A3.y);
      float gg = tanhf(A3.z),     og = sigmoidf_(A3.w);
      float cn = fg * c3 + ig * gg; c3 = cn;
      hn[(ub + 3) * 16 + rr] = og * tanhf(cn);
    }
    __syncthreads();                 // h(t+1) visible; old buffer free
    cur ^= 1;
    tok1 = tok2;
  }

  // final hidden state is in hs[0] after 64 flips; coalesced write
  for (int i = tid; i < 1024; i += 256) {
    int u = i & 63, r2 = i >> 6;
    eOut[(size_t)(rbase + r2) * 64 + u] = hs[0][u * 16 + r2];
  }
}

// ---------------- Kernel 3: attention MLP logits, one thread per (row, cell) ----------------
__global__ __launch_bounds__(256) void k_attlog(
    const float* __restrict__ eOut, const float* __restrict__ canvas,
    const float* __restrict__ Wr1, const float* __restrict__ br1,
    const float* __restrict__ Wr2, const float* __restrict__ br2,
    float* __restrict__ attL, int total) {
  const int gid = blockIdx.x * 256 + threadIdx.x;
  if (gid >= total) return;
  const int rrow = gid / 25, cell = gid - rrow * 25;
  const float* e  = eOut + (size_t)rrow * 64;
  const float* cv = canvas + (size_t)rrow * 100 + cell * 4;
  float cv0 = cv[0], cv1 = cv[1], cv2 = cv[2], cv3 = cv[3];

  float h[32];
  #pragma unroll
  for (int j4 = 0; j4 < 8; ++j4) {
    float4 b4 = ((const float4*)br1)[j4];
    float4 w64 = ((const float4*)(Wr1 + 64 * 32))[j4];
    float4 w65 = ((const float4*)(Wr1 + 65 * 32))[j4];
    float4 w66 = ((const float4*)(Wr1 + 66 * 32))[j4];
    float4 w67 = ((const float4*)(Wr1 + 67 * 32))[j4];
    h[j4*4+0] = fmaf(cv3, w67.x, fmaf(cv2, w66.x, fmaf(cv1, w65.x, fmaf(cv0, w64.x, b4.x))));
    h[j4*4+1] = fmaf(cv3, w67.y, fmaf(cv2, w66.y, fmaf(cv1, w65.y, fmaf(cv0, w64.y, b4.y))));
    h[j4*4+2] = fmaf(cv3, w67.z, fmaf(cv2, w66.z, fmaf(cv1, w65.z, fmaf(cv0, w64.z, b4.z))));
    h[j4*4+3] = fmaf(cv3, w67.w, fmaf(cv2, w66.w, fmaf(cv1, w65.w, fmaf(cv0, w64.w, b4.w))));
  }
  for (int k = 0; k < 64; ++k) {
    float ek = e[k];
    const float4* wrow = (const float4*)(Wr1 + k * 32);
    #pragma unroll
    for (int j4 = 0; j4 < 8; ++j4) {
      float4 w = wrow[j4];
      h[j4*4+0] = fmaf(ek, w.x, h[j4*4+0]);
      h[j4*4+1] = fmaf(ek, w.y, h[j4*4+1]);
      h[j4*4+2] = fmaf(ek, w.z, h[j4*4+2]);
      h[j4*4+3] = fmaf(ek, w.w, h[j4*4+3]);
    }
  }
  float logit = br2[0];
  #pragma unroll
  for (int j = 0; j < 32; ++j) logit = fmaf(fmaxf(h[j], 0.f), Wr2[j], logit);
  attL[gid] = logit;
}

// ---------------- Kernel 4: heads + sampling + index_join, one thread per row ----------------
__global__ __launch_bounds__(256) void k_heads(
    const float* __restrict__ eOut, const float* __restrict__ canvas,
    const int* __restrict__ inst_type,
    const float* __restrict__ Wc, const float* __restrict__ bc,
    const float* __restrict__ Wsh, const float* __restrict__ bsh,
    const float* __restrict__ Wa, const float* __restrict__ ba,
    const float* __restrict__ Wl, const float* __restrict__ bl,
    const float* __restrict__ Wr, const float* __restrict__ br,
    const float* __restrict__ attL, float* __restrict__ out, int B) {
  const int r = blockIdx.x * 256 + threadIdx.x;
  if (r >= B) return;
  const float* e = eOut + (size_t)r * 64;

  uint2 kc  = threefry2x32(0u, 42u, 0u, 0u);
  uint2 ksh = threefry2x32(0u, 42u, 0u, 1u);
  uint2 kac = threefry2x32(0u, 42u, 0u, 2u);
  uint2 kab = threefry2x32(0u, 42u, 0u, 3u);
  uint2 krl = threefry2x32(0u, 42u, 0u, 4u);
  uint2 kat = threefry2x32(0u, 42u, 0u, 5u);

  float lc[3]  = {bc[0], bc[1], bc[2]};
  float lsh[3] = {bsh[0], bsh[1], bsh[2]};
  float lac[2] = {ba[0], ba[1]};
  float ll[25];
  #pragma unroll
  for (int j = 0; j < 25; ++j) ll[j] = bl[j];
  float lrr[8];
  #pragma unroll
  for (int j = 0; j < 8; ++j) lrr[j] = br[j];

  for (int k = 0; k < 64; ++k) {
    float ek = e[k];
    #pragma unroll
    for (int j = 0; j < 3; ++j)  lc[j]  = fmaf(ek, Wc[k * 3 + j],  lc[j]);
    #pragma unroll
    for (int j = 0; j < 3; ++j)  lsh[j] = fmaf(ek, Wsh[k * 3 + j], lsh[j]);
    #pragma unroll
    for (int j = 0; j < 2; ++j)  lac[j] = fmaf(ek, Wa[k * 2 + j],  lac[j]);
    #pragma unroll
    for (int j = 0; j < 25; ++j) ll[j]  = fmaf(ek, Wl[k * 25 + j], ll[j]);
    #pragma unroll
    for (int j = 0; j < 8; ++j)  lrr[j] = fmaf(ek, Wr[k * 8 + j],  lrr[j]);
  }

  int s_color, s_shape, s_act, s_abs, s_rel, s_att;
  float lp_color, lp_shape, lp_act, lp_abs, lp_rel, lp_att;
  sample_head<3>(lc,  kc.x,  kc.y,  r, s_color, lp_color);
  sample_head<3>(lsh, ksh.x, ksh.y, r, s_shape, lp_shape);
  sample_head<2>(lac, kac.x, kac.y, r, s_act,   lp_act);
  sample_head<25>(ll, kab.x, kab.y, r, s_abs,   lp_abs);
  sample_head<8>(lrr, krl.x, krl.y, r, s_rel,   lp_rel);

  float lat[25];
  #pragma unroll
  for (int j = 0; j < 25; ++j) lat[j] = attL[(size_t)r * 25 + j];
  sample_head<25>(lat, kat.x, kat.y, r, s_att, lp_att);

  const float* cvp = canvas + (size_t)r * 100 + s_att * 4;
  int ref_r = (int)cvp[2];
  int ref_c = (int)cvp[3];
  int dr = (int)((0x22001120u >> (4 * s_rel)) & 15u) - 1;
  int dc = (int)((0x20200211u >> (4 * s_rel)) & 15u) - 1;
  int rel_loc = (ref_r + dr) * 5 + (ref_c + dc);

  bool isrel = (inst_type[r] == 2);
  out[(size_t)r * 5 + 0] = lp_color;
  out[(size_t)r * 5 + 1] = lp_shape;
  out[(size_t)r * 5 + 2] = lp_act;
  out[(size_t)r * 5 + 3] = isrel ? lp_rel : lp_abs;
  out[(size_t)r * 5 + 4] = isrel ? lp_att : 0.f;
  out[(size_t)B * 5 + r] = (float)(isrel ? rel_loc : s_abs);
}

// ---------------- launch ----------------
extern "C" void kernel_launch(void* const* d_in, const int* in_sizes, int n_in,
                              void* d_out, int out_size, void* d_ws, size_t ws_size,
                              hipStream_t stream) {
  (void)n_in; (void)out_size; (void)ws_size;
  const int*   inst      = (const int*)  d_in[0];
  const float* canvas    = (const float*)d_in[1];
  const int*   inst_type = (const int*)  d_in[2];
  const float* embed     = (const float*)d_in[3];
  const float* W_ih      = (const float*)d_in[4];
  const float* W_hh      = (const float*)d_in[5];
  const float* b_ih      = (const float*)d_in[6];
  const float* b_hh      = (const float*)d_in[7];
  const float* Wc  = (const float*)d_in[8];  const float* bc  = (const float*)d_in[9];
  const float* Wsh = (const float*)d_in[10]; const float* bsh = (const float*)d_in[11];
  const float* Wa  = (const float*)d_in[12]; const float* ba  = (const float*)d_in[13];
  const float* Wl  = (const float*)d_in[14]; const float* bl  = (const float*)d_in[15];
  const float* Wr  = (const float*)d_in[16]; const float* br  = (const float*)d_in[17];
  const float* Wr1 = (const float*)d_in[18]; const float* br1 = (const float*)d_in[19];
  const float* Wr2 = (const float*)d_in[20]; const float* br2 = (const float*)d_in[21];

  const int B  = in_sizes[0] / 64;   // 16384
  const int NV = in_sizes[3] / 64;   // 32001

  // workspace: embedW (NV*256 f32 ~31.3MB) | eOut (B*64 ~4MB) | attL (B*25 ~1.6MB) | wt (64KB)
  float* embedWG = (float*)d_ws;
  float* eOut    = embedWG + (size_t)NV * 256;
  float* attL    = eOut + (size_t)B * 64;
  float* wtbuf   = attL + (size_t)B * 25;
  float* out     = (float*)d_out;

  k_embedw<<<(NV + 125) / 126, 1024, 0, stream>>>(embed, W_ih, b_ih, b_hh, embedWG, NV);
  k_wt<<<16, 1024, 0, stream>>>(W_hh, wtbuf);
  k_lstm64<<<B / 16, 256, 0, stream>>>(inst, wtbuf, embedWG, eOut);
  {
    int total = B * 25;
    k_attlog<<<(total + 255) / 256, 256, 0, stream>>>(eOut, canvas, Wr1, br1, Wr2, br2,
                                                      attL, total);
  }
  k_heads<<<(B + 255) / 256, 256, 0, stream>>>(eOut, canvas, inst_type,
                                               Wc, bc, Wsh, bsh, Wa, ba, Wl, bl, Wr, br,
                                               attL, out, B);
}